// Round 1
// baseline (50.727 us; speedup 1.0000x reference)
//
#include <hip/hip_runtime.h>
#include <hip/hip_bf16.h>

#define E_TOT 50000
#define NF    64
#define B_TOT 64
#define B_TILE 16
#define BLOCK 256

// out[b,e] = sum_f exp(-(HL[b,f] - NL[e,f] - c[f])^2 / var[f]) * W[b,f]
// Folding: q[f] = sqrt(log2e / var[f]);  A[b,f] = (HL[b,f]-c[f])*q[f];
//          nlq[e,f] = NL[e,f]*q[f];  phi = exp2(-(A-nlq)^2)
// Per element: v_sub, v_mul, v_exp (neg mod), v_fmac  -> compute-bound.
__global__ __launch_bounds__(BLOCK, 4)
void kbln_kernel(const float* __restrict__ NL,     // [E, F]
                 const float* __restrict__ c,      // [F]
                 const float* __restrict__ varr,   // [F]
                 const float* __restrict__ NFW,    // [R, F]
                 const int*   __restrict__ head_ids, // [B]
                 const int*   __restrict__ rel_ids,  // [B]
                 float*       __restrict__ out)    // [B, E]
{
    __shared__ float sQ[NF];
    __shared__ float sA[B_TILE][NF];
    __shared__ float sW[B_TILE][NF];

    const int tid = threadIdx.x;
    const int b0  = blockIdx.y * B_TILE;
    const int e   = blockIdx.x * BLOCK + tid;

    // q[f] = sqrt(log2e / var[f])
    if (tid < NF) {
        sQ[tid] = sqrtf(1.4426950408889634f / varr[tid]);
    }
    __syncthreads();

    // Stage A (folded head literals) and W for this block's 16 b's.
    // i = bi*64 + f; lanes walk f -> coalesced gather of NL/NFW rows.
    for (int i = tid; i < B_TILE * NF; i += BLOCK) {
        const int bi = i >> 6;
        const int f  = i & (NF - 1);
        const int h  = head_ids[b0 + bi];
        const int r  = rel_ids[b0 + bi];
        sA[bi][f] = (NL[(size_t)h * NF + f] - c[f]) * sQ[f];
        sW[bi][f] = NFW[(size_t)r * NF + f];
    }
    __syncthreads();

    if (e >= E_TOT) return;  // no barriers below this point

    // Per-thread: own NL row, pre-multiplied by q. 16 float4 = 64 VGPR.
    float4 nlq[NF / 4];
    const float4* nl4 = reinterpret_cast<const float4*>(NL + (size_t)e * NF);
    const float4* q4  = reinterpret_cast<const float4*>(sQ);
#pragma unroll
    for (int i = 0; i < NF / 4; ++i) {
        const float4 v = nl4[i];
        const float4 q = q4[i];
        nlq[i].x = v.x * q.x;
        nlq[i].y = v.y * q.y;
        nlq[i].z = v.z * q.z;
        nlq[i].w = v.w * q.w;
    }

    for (int bi = 0; bi < B_TILE; ++bi) {
        const float4* a4 = reinterpret_cast<const float4*>(&sA[bi][0]);
        const float4* w4 = reinterpret_cast<const float4*>(&sW[bi][0]);
        float acc = 0.0f;
#pragma unroll
        for (int i = 0; i < NF / 4; ++i) {
            const float4 a = a4[i];   // LDS broadcast, ds_read_b128
            const float4 w = w4[i];
            float t;
            t = a.x - nlq[i].x; acc = fmaf(__builtin_amdgcn_exp2f(-(t * t)), w.x, acc);
            t = a.y - nlq[i].y; acc = fmaf(__builtin_amdgcn_exp2f(-(t * t)), w.y, acc);
            t = a.z - nlq[i].z; acc = fmaf(__builtin_amdgcn_exp2f(-(t * t)), w.z, acc);
            t = a.w - nlq[i].w; acc = fmaf(__builtin_amdgcn_exp2f(-(t * t)), w.w, acc);
        }
        out[(size_t)(b0 + bi) * E_TOT + e] = acc;
    }
}

extern "C" void kernel_launch(void* const* d_in, const int* in_sizes, int n_in,
                              void* d_out, int out_size, void* d_ws, size_t ws_size,
                              hipStream_t stream)
{
    const float* NL       = (const float*)d_in[0];
    const float* c        = (const float*)d_in[1];
    const float* varr     = (const float*)d_in[2];
    const float* NFW      = (const float*)d_in[3];
    const int*   head_ids = (const int*)d_in[4];
    const int*   rel_ids  = (const int*)d_in[5];
    float*       out      = (float*)d_out;

    dim3 grid((E_TOT + BLOCK - 1) / BLOCK, B_TOT / B_TILE);
    kbln_kernel<<<grid, dim3(BLOCK), 0, stream>>>(NL, c, varr, NFW, head_ids, rel_ids, out);
}

// Round 2
// 39.644 us; speedup vs baseline: 1.2796x; 1.2796x over previous
//
#include <hip/hip_runtime.h>
#include <hip/hip_bf16.h>

#define E_TOT 50000
#define NF    64
#define B_TOT 64
#define B_TILE 8
#define BLOCK 256

// out[b,e] = sum_f exp(-(HL[b,f] - NL[e,f] - c[f])^2 / var[f]) * W[b,f]
// Folding: q[f] = sqrt(log2e / var[f]);  A[b,f] = (HL[b,f]-c[f])*q[f];
//          nlq[e,f] = NL[e,f]*q[f];  phi = exp2(-(A-nlq)^2)
// Per element: v_sub, v_mul, v_exp (neg modifier), v_fmac.
// Structure: i(f-chunk)-outer, bi-inner -> B_TILE independent acc chains,
// ~30 VGPRs -> 8 waves/SIMD schedulable; grid 196x8=1568 blocks for occupancy.
__global__ __launch_bounds__(BLOCK, 8)
void kbln_kernel(const float* __restrict__ NL,       // [E, F]
                 const float* __restrict__ c,        // [F]
                 const float* __restrict__ varr,     // [F]
                 const float* __restrict__ NFW,      // [R, F]
                 const int*   __restrict__ head_ids, // [B]
                 const int*   __restrict__ rel_ids,  // [B]
                 float*       __restrict__ out)      // [B, E]
{
    __shared__ float sQ[NF];
    __shared__ float4 sA[B_TILE][NF / 4];
    __shared__ float4 sW[B_TILE][NF / 4];

    const int tid = threadIdx.x;
    const int b0  = blockIdx.y * B_TILE;
    const int e   = blockIdx.x * BLOCK + tid;

    if (tid < NF) {
        sQ[tid] = sqrtf(1.4426950408889634f / varr[tid]);
    }
    __syncthreads();

    // Stage folded head literals A and weights W for this block's 8 b's.
    for (int i = tid; i < B_TILE * NF; i += BLOCK) {
        const int bi = i >> 6;
        const int f  = i & (NF - 1);
        const int h  = head_ids[b0 + bi];
        const int r  = rel_ids[b0 + bi];
        reinterpret_cast<float*>(&sA[bi][0])[f] =
            (NL[(size_t)h * NF + f] - c[f]) * sQ[f];
        reinterpret_cast<float*>(&sW[bi][0])[f] = NFW[(size_t)r * NF + f];
    }
    __syncthreads();

    if (e >= E_TOT) return;  // no barriers below

    const float4* nl4 = reinterpret_cast<const float4*>(NL + (size_t)e * NF);
    const float4* q4  = reinterpret_cast<const float4*>(sQ);

    float acc[B_TILE];
#pragma unroll
    for (int bi = 0; bi < B_TILE; ++bi) acc[bi] = 0.0f;

#pragma unroll
    for (int i = 0; i < NF / 4; ++i) {
        const float4 v = nl4[i];   // streamed global load (keeps VGPR low)
        const float4 q = q4[i];    // LDS broadcast
        float4 n;
        n.x = v.x * q.x; n.y = v.y * q.y; n.z = v.z * q.z; n.w = v.w * q.w;
#pragma unroll
        for (int bi = 0; bi < B_TILE; ++bi) {
            const float4 a = sA[bi][i];  // ds_read_b128 broadcast
            const float4 w = sW[bi][i];
            float t;
            t = a.x - n.x; acc[bi] = fmaf(__builtin_amdgcn_exp2f(-(t * t)), w.x, acc[bi]);
            t = a.y - n.y; acc[bi] = fmaf(__builtin_amdgcn_exp2f(-(t * t)), w.y, acc[bi]);
            t = a.z - n.z; acc[bi] = fmaf(__builtin_amdgcn_exp2f(-(t * t)), w.z, acc[bi]);
            t = a.w - n.w; acc[bi] = fmaf(__builtin_amdgcn_exp2f(-(t * t)), w.w, acc[bi]);
        }
    }

#pragma unroll
    for (int bi = 0; bi < B_TILE; ++bi) {
        out[(size_t)(b0 + bi) * E_TOT + e] = acc[bi];
    }
}

extern "C" void kernel_launch(void* const* d_in, const int* in_sizes, int n_in,
                              void* d_out, int out_size, void* d_ws, size_t ws_size,
                              hipStream_t stream)
{
    const float* NL       = (const float*)d_in[0];
    const float* c        = (const float*)d_in[1];
    const float* varr     = (const float*)d_in[2];
    const float* NFW      = (const float*)d_in[3];
    const int*   head_ids = (const int*)d_in[4];
    const int*   rel_ids  = (const int*)d_in[5];
    float*       out      = (float*)d_out;

    dim3 grid((E_TOT + BLOCK - 1) / BLOCK, B_TOT / B_TILE);
    kbln_kernel<<<grid, dim3(BLOCK), 0, stream>>>(NL, c, varr, NFW, head_ids, rel_ids, out);
}